// Round 3
// baseline (810.549 us; speedup 1.0000x reference)
//
#include <hip/hip_runtime.h>

#define PTOT 131072      // B*H*W
#define IMGP 16384       // H*W
#define BATCH 8
#define EPSV 1e-5f

typedef short bf16x8 __attribute__((ext_vector_type(8)));
typedef float f32x4 __attribute__((ext_vector_type(4)));

__device__ __forceinline__ float bf2f(unsigned short u){
  union { unsigned int i; float f; } v; v.i = ((unsigned int)u) << 16; return v.f;
}
__device__ __forceinline__ unsigned short f2bf(float f){
  union { float f; unsigned int i; } v; v.f = f;
  unsigned int r = v.i + 0x7FFFu + ((v.i >> 16) & 1u);
  return (unsigned short)(r >> 16);
}
__device__ __forceinline__ unsigned int pk2(float a, float b){
  return (unsigned int)f2bf(a) | ((unsigned int)f2bf(b) << 16);
}
__device__ __forceinline__ float sigmoidf_(float x){ return 1.f/(1.f + __expf(-x)); }

__device__ __forceinline__ void ld16bf(const unsigned short* p, float* f){
  uint4 u0 = *(const uint4*)p;
  uint4 u1 = *(const uint4*)(p+8);
  f[0]=bf2f((unsigned short)u0.x); f[1]=bf2f((unsigned short)(u0.x>>16));
  f[2]=bf2f((unsigned short)u0.y); f[3]=bf2f((unsigned short)(u0.y>>16));
  f[4]=bf2f((unsigned short)u0.z); f[5]=bf2f((unsigned short)(u0.z>>16));
  f[6]=bf2f((unsigned short)u0.w); f[7]=bf2f((unsigned short)(u0.w>>16));
  f[8]=bf2f((unsigned short)u1.x); f[9]=bf2f((unsigned short)(u1.x>>16));
  f[10]=bf2f((unsigned short)u1.y); f[11]=bf2f((unsigned short)(u1.y>>16));
  f[12]=bf2f((unsigned short)u1.z); f[13]=bf2f((unsigned short)(u1.z>>16));
  f[14]=bf2f((unsigned short)u1.w); f[15]=bf2f((unsigned short)(u1.w>>16));
}

// ---------------- weight prep: fp32 -> bf16, concatenated ----------------
// offsets (elems): spec 0, qkv 16384, proj 65536, mlp1 81920, mlp2 147456, pw 212992; total 229376
__global__ __launch_bounds__(256) void k_prep(
    const float* __restrict__ a0, const float* __restrict__ a1,
    const float* __restrict__ a2, const float* __restrict__ a3,
    const float* __restrict__ a4, const float* __restrict__ a5,
    unsigned short* __restrict__ dst)
{
  int i = blockIdx.x*256 + threadIdx.x;
  if (i >= 229376) return;
  float v;
  if (i < 16384) v = a0[i];
  else if (i < 65536) v = a1[i-16384];
  else if (i < 81920) v = a2[i-65536];
  else if (i < 147456) v = a3[i-81920];
  else if (i < 212992) v = a4[i-147456];
  else v = a5[i-212992];
  dst[i] = f2bf(v);
}

// ---------------- time MLP: all 3 stages ----------------
__global__ __launch_bounds__(256) void k_time_mlp(
    const float* __restrict__ temb,
    const float* __restrict__ w1a, const float* __restrict__ b1a,
    const float* __restrict__ w2a, const float* __restrict__ b2a,
    const float* __restrict__ w1b, const float* __restrict__ b1b,
    const float* __restrict__ w2b, const float* __restrict__ b2b,
    const float* __restrict__ w1c, const float* __restrict__ b1c,
    const float* __restrict__ w2c, const float* __restrict__ b2c,
    float* __restrict__ scsh)
{
  int b = blockIdx.x, s = blockIdx.y, t = threadIdx.x;
  const float* w1 = (s==0)? w1a : ((s==1)? w1b : w1c);
  const float* b1 = (s==0)? b1a : ((s==1)? b1b : b1c);
  const float* w2 = (s==0)? w2a : ((s==1)? w2b : w2c);
  const float* b2 = (s==0)? b2a : ((s==1)? b2b : b2c);
  __shared__ float te[256];
  __shared__ float hb[512];
  te[t] = temb[b*256 + t];
  __syncthreads();
  for (int k = t; k < 512; k += 256){
    float acc = b1[k];
    const float* wr = w1 + (size_t)k*256;
    for (int j = 0; j < 256; j += 4){
      float4 w = *(const float4*)(wr + j);
      acc += w.x*te[j] + w.y*te[j+1] + w.z*te[j+2] + w.w*te[j+3];
    }
    hb[k] = acc * sigmoidf_(acc);
  }
  __syncthreads();
  {
    float acc = b2[t];
    const float* wr = w2 + (size_t)t*512;
    for (int j = 0; j < 512; j += 4){
      float4 w = *(const float4*)(wr + j);
      acc += w.x*hb[j] + w.y*hb[j+1] + w.z*hb[j+2] + w.w*hb[j+3];
    }
    scsh[(size_t)(s*BATCH + b)*256 + t] = acc;
  }
}

// ---------------- k_pre: x0 [c][hw] -> X0T [p'][128] (window-major) + SG1 raw sums ----------------
__global__ __launch_bounds__(256) void k_pre(
    const float* __restrict__ x0, float* __restrict__ X0T, float* __restrict__ SG1)
{
  __shared__ __align__(16) float T[64*136];
  __shared__ float sgS[32], sgSS[32];
  int t = threadIdx.x;
  int p0 = blockIdx.x << 6;
  int b = p0 >> 14;
  int win0 = (p0 >> 4) & 1023;
  int wh = win0 >> 5, ww0 = win0 & 31;
  if (t < 32){ sgS[t]=0.f; sgSS[t]=0.f; }
  int q = t & 3;
  int cb = t >> 2;
  #pragma unroll
  for (int ci = 0; ci < 2; ++ci){
    int c = cb + ci*64;
    const float* src = x0 + ((size_t)(b*128 + c))*IMGP + (wh*4)*128 + ww0*4 + q*4;
    #pragma unroll
    for (int ty = 0; ty < 4; ++ty){
      float4 v = *(const float4*)(src + ty*128);
      T[(q*16 + ty*4 + 0)*136 + c] = v.x;
      T[(q*16 + ty*4 + 1)*136 + c] = v.y;
      T[(q*16 + ty*4 + 2)*136 + c] = v.z;
      T[(q*16 + ty*4 + 3)*136 + c] = v.w;
    }
  }
  __syncthreads();
  {
    int px = t >> 2, c0 = (t & 3) << 5;
    float* dst = X0T + ((size_t)(p0+px))*128 + c0;
    const float* src = T + px*136 + c0;
    #pragma unroll
    for (int gi = 0; gi < 8; ++gi){
      float4 v = *(const float4*)(src + gi*4);
      *(float4*)(dst + gi*4) = v;
      atomicAdd(&sgS[(c0>>2)+gi],  v.x+v.y+v.z+v.w);
      atomicAdd(&sgSS[(c0>>2)+gi], v.x*v.x+v.y*v.y+v.z*v.z+v.w*v.w);
    }
  }
  __syncthreads();
  if (t < 32){
    atomicAdd(&SG1[(b*32+t)*2],   sgS[t]);
    atomicAdd(&SG1[(b*32+t)*2+1], sgSS[t]);
  }
}

// ---------------- S1: AdaGN*sig(modew) -> spec 1x1 -> silu -> +x0 => XR, + SG2 stats ----------------
__global__ __launch_bounds__(256) void k_s1(
    const float* __restrict__ X0T,
    const float* __restrict__ SG1, float* __restrict__ SG2,
    const unsigned short* __restrict__ Wbf, const float* __restrict__ bias,
    const float* __restrict__ gnw, const float* __restrict__ gnb,
    const float* __restrict__ scsh, const float* __restrict__ modew,
    float* __restrict__ XR)
{
  __shared__ __align__(16) unsigned short Bs[64*136];
  __shared__ __align__(16) char UN[64*136*4];   // As [128][72] bf16 | OT [64][136] f32
  __shared__ float An[128], Bn[128];
  __shared__ float sgS[32], sgSS[32];
  unsigned short* As = (unsigned short*)UN;
  float* OT = (float*)UN;
  int t = threadIdx.x;
  int p0 = blockIdx.x << 6;
  int b = p0 >> 14;
  if (t < 128){
    int g = t >> 2;
    float S = SG1[(b*32+g)*2], SS = SG1[(b*32+g)*2+1];
    float m = S*(1.f/65536.f);
    float r = rsqrtf(SS*(1.f/65536.f) - m*m + EPSV);
    float sc = 1.f + scsh[b*256 + t];
    float sh = scsh[b*256 + 128 + t];
    float a = r*gnw[t]*sc;
    float bb = (gnb[t] - m*r*gnw[t])*sc + sh;
    float sg = sigmoidf_(modew[t]); a *= sg; bb *= sg;
    An[t] = a; Bn[t] = bb;
  }
  if (t < 32){ sgS[t]=0.f; sgSS[t]=0.f; }
  __syncthreads();
  {
    int px = t >> 2, c0 = (t & 3) << 5;
    const float* src = X0T + ((size_t)(p0+px))*128 + c0;
    unsigned short* dst = Bs + px*136 + c0;
    #pragma unroll
    for (int j = 0; j < 4; ++j){
      float4 v0 = *(const float4*)(src + j*8);
      float4 v1 = *(const float4*)(src + j*8 + 4);
      int c = c0 + j*8;
      uint4 w;
      w.x = pk2(fmaf(v0.x,An[c+0],Bn[c+0]), fmaf(v0.y,An[c+1],Bn[c+1]));
      w.y = pk2(fmaf(v0.z,An[c+2],Bn[c+2]), fmaf(v0.w,An[c+3],Bn[c+3]));
      w.z = pk2(fmaf(v1.x,An[c+4],Bn[c+4]), fmaf(v1.y,An[c+5],Bn[c+5]));
      w.w = pk2(fmaf(v1.z,An[c+6],Bn[c+6]), fmaf(v1.w,An[c+7],Bn[c+7]));
      *(uint4*)(dst + j*8) = w;
    }
  }
  f32x4 acc[2][4];
  #pragma unroll
  for (int i=0;i<2;++i)
    #pragma unroll
    for (int j=0;j<4;++j){ f32x4 z={0.f,0.f,0.f,0.f}; acc[i][j]=z; }
  int lane = t & 63, wv = t >> 6, quad = lane >> 4, l15 = lane & 15;
  for (int kc = 0; kc < 2; ++kc){
    __syncthreads();
    {
      int o = t >> 1, k0 = (t & 1) << 5;
      const unsigned short* src = Wbf + o*128 + kc*64 + k0;
      unsigned short* dst = As + o*72 + k0;
      #pragma unroll
      for (int j = 0; j < 4; ++j) *(uint4*)(dst + j*8) = *(const uint4*)(src + j*8);
    }
    __syncthreads();
    #pragma unroll
    for (int s = 0; s < 2; ++s){
      bf16x8 af[2], bfv[4];
      #pragma unroll
      for (int i=0;i<2;++i) af[i] = *(const bf16x8*)(As + (wv*32 + i*16 + l15)*72 + s*32 + quad*8);
      #pragma unroll
      for (int j=0;j<4;++j) bfv[j] = *(const bf16x8*)(Bs + (j*16 + l15)*136 + kc*64 + s*32 + quad*8);
      #pragma unroll
      for (int i=0;i<2;++i)
        #pragma unroll
        for (int j=0;j<4;++j)
          acc[i][j] = __builtin_amdgcn_mfma_f32_16x16x32_bf16(af[i], bfv[j], acc[i][j], 0,0,0);
    }
  }
  __syncthreads();
  #pragma unroll
  for (int i = 0; i < 2; ++i){
    int o = wv*32 + i*16 + (quad<<2);
    float4 bv = *(const float4*)(bias + o);
    #pragma unroll
    for (int j = 0; j < 4; ++j){
      int px = j*16 + l15;
      float v0=acc[i][j][0]+bv.x, v1=acc[i][j][1]+bv.y, v2=acc[i][j][2]+bv.z, v3=acc[i][j][3]+bv.w;
      v0*=sigmoidf_(v0); v1*=sigmoidf_(v1); v2*=sigmoidf_(v2); v3*=sigmoidf_(v3);
      float4 rv = *(const float4*)(X0T + ((size_t)(p0+px))*128 + o);
      v0+=rv.x; v1+=rv.y; v2+=rv.z; v3+=rv.w;
      *(float4*)(OT + px*136 + o) = make_float4(v0,v1,v2,v3);
    }
  }
  __syncthreads();
  {
    int px = t >> 2, c0 = (t & 3) << 5;
    float* dst = XR + ((size_t)(p0+px))*128 + c0;
    const float* src = OT + px*136 + c0;
    #pragma unroll
    for (int gi = 0; gi < 8; ++gi){
      float4 v = *(const float4*)(src + gi*4);
      *(float4*)(dst + gi*4) = v;
      atomicAdd(&sgS[(c0>>2)+gi],  v.x+v.y+v.z+v.w);
      atomicAdd(&sgSS[(c0>>2)+gi], v.x*v.x+v.y*v.y+v.z*v.z+v.w*v.w);
    }
  }
  __syncthreads();
  if (t < 32){
    atomicAdd(&SG2[(b*32+t)*2],   sgS[t]);
    atomicAdd(&SG2[(b*32+t)*2+1], sgSS[t]);
  }
}

// ---------------- S2: AdaGN -> qkv -> window-attn -> proj -> +x => XR, + SG3 stats ----------------
__global__ __launch_bounds__(256) void k_s2(
    float* __restrict__ XR,
    const float* __restrict__ SG2, float* __restrict__ SG3,
    const unsigned short* __restrict__ Wqkv, const float* __restrict__ bqkv,
    const unsigned short* __restrict__ Wproj, const float* __restrict__ bproj,
    const float* __restrict__ relb,
    const float* __restrict__ gnw, const float* __restrict__ gnb,
    const float* __restrict__ scsh)
{
  __shared__ __align__(16) unsigned short Bs[32*136];
  __shared__ __align__(16) unsigned short QB[32*136];
  __shared__ __align__(16) unsigned short KB[32*136];
  __shared__ __align__(16) unsigned short VB[32*136];
  __shared__ __align__(16) char UN[18432];  // As [128][72] bf16 | OT [32][136] f32
  __shared__ float An[128], Bn[128];
  __shared__ float relbs[392];
  __shared__ float sgS[32], sgSS[32];
  unsigned short* As = (unsigned short*)UN;
  float* OT = (float*)UN;
  int t = threadIdx.x;
  int p0 = blockIdx.x << 5;
  int b = p0 >> 14;
  if (t < 128){
    int g = t >> 2;
    float S = SG2[(b*32+g)*2], SS = SG2[(b*32+g)*2+1];
    float m = S*(1.f/65536.f);
    float r = rsqrtf(SS*(1.f/65536.f) - m*m + EPSV);
    float sc = 1.f + scsh[b*256 + t];
    float sh = scsh[b*256 + 128 + t];
    An[t] = r*gnw[t]*sc;
    Bn[t] = (gnb[t] - m*r*gnw[t])*sc + sh;
  }
  for (int j = t; j < 392; j += 256) relbs[j] = relb[j];
  if (t < 32){ sgS[t]=0.f; sgSS[t]=0.f; }
  __syncthreads();
  {
    int px = t >> 3, c0 = (t & 7) << 4;
    const float* src = XR + ((size_t)(p0+px))*128 + c0;
    unsigned short* dst = Bs + px*136 + c0;
    #pragma unroll
    for (int j = 0; j < 2; ++j){
      float4 v0 = *(const float4*)(src + j*8);
      float4 v1 = *(const float4*)(src + j*8 + 4);
      int c = c0 + j*8;
      uint4 w;
      w.x = pk2(fmaf(v0.x,An[c+0],Bn[c+0]), fmaf(v0.y,An[c+1],Bn[c+1]));
      w.y = pk2(fmaf(v0.z,An[c+2],Bn[c+2]), fmaf(v0.w,An[c+3],Bn[c+3]));
      w.z = pk2(fmaf(v1.x,An[c+4],Bn[c+4]), fmaf(v1.y,An[c+5],Bn[c+5]));
      w.w = pk2(fmaf(v1.z,An[c+6],Bn[c+6]), fmaf(v1.w,An[c+7],Bn[c+7]));
      *(uint4*)(dst + j*8) = w;
    }
  }
  int lane = t & 63, wv = t >> 6, quad = lane >> 4, l15 = lane & 15;
  unsigned short* bufs[3] = {QB, KB, VB};
  for (int s = 0; s < 3; ++s){
    f32x4 acc[2][2];
    #pragma unroll
    for (int i=0;i<2;++i)
      #pragma unroll
      for (int j=0;j<2;++j){ f32x4 z={0.f,0.f,0.f,0.f}; acc[i][j]=z; }
    for (int kc = 0; kc < 2; ++kc){
      __syncthreads();
      {
        int o = t >> 1, k0 = (t & 1) << 5;
        const unsigned short* src = Wqkv + (size_t)(s*128+o)*128 + kc*64 + k0;
        unsigned short* dst = As + o*72 + k0;
        #pragma unroll
        for (int j = 0; j < 4; ++j) *(uint4*)(dst + j*8) = *(const uint4*)(src + j*8);
      }
      __syncthreads();
      #pragma unroll
      for (int ks = 0; ks < 2; ++ks){
        bf16x8 af[2], bfv[2];
        #pragma unroll
        for (int i=0;i<2;++i) af[i] = *(const bf16x8*)(As + (wv*32 + i*16 + l15)*72 + ks*32 + quad*8);
        #pragma unroll
        for (int j=0;j<2;++j) bfv[j] = *(const bf16x8*)(Bs + (j*16 + l15)*136 + kc*64 + ks*32 + quad*8);
        #pragma unroll
        for (int i=0;i<2;++i)
          #pragma unroll
          for (int j=0;j<2;++j)
            acc[i][j] = __builtin_amdgcn_mfma_f32_16x16x32_bf16(af[i], bfv[j], acc[i][j], 0,0,0);
      }
    }
    unsigned short* dstb = bufs[s];
    #pragma unroll
    for (int i = 0; i < 2; ++i){
      int o = wv*32 + i*16 + (quad<<2);
      float4 bv = *(const float4*)(bqkv + s*128 + o);
      #pragma unroll
      for (int j = 0; j < 2; ++j){
        int px = j*16 + l15;
        *(unsigned int*)(dstb + px*136 + o)     = pk2(acc[i][j][0]+bv.x, acc[i][j][1]+bv.y);
        *(unsigned int*)(dstb + px*136 + o + 2) = pk2(acc[i][j][2]+bv.z, acc[i][j][3]+bv.w);
      }
    }
  }
  __syncthreads();
  // attention: 2 windows x 8 heads x 16 tq = 256 items
  {
    int win = t >> 7, head = (t >> 4) & 7, tq = t & 15;
    float qv[16];
    ld16bf(QB + (win*16+tq)*136 + head*16, qv);
    float pr[16]; float mx = -1e30f;
    int ty = tq >> 2, tx = tq & 3;
    #pragma unroll
    for (int s16 = 0; s16 < 16; ++s16){
      float kv[16];
      ld16bf(KB + (win*16+s16)*136 + head*16, kv);
      float dot = 0.f;
      #pragma unroll
      for (int d = 0; d < 16; ++d) dot = fmaf(qv[d], kv[d], dot);
      int idx = (ty-(s16>>2)+3)*7 + (tx-(s16&3)+3);
      pr[s16] = dot*0.25f + relbs[idx*8 + head];
      mx = fmaxf(mx, pr[s16]);
    }
    float sum = 0.f;
    #pragma unroll
    for (int s16 = 0; s16 < 16; ++s16){ pr[s16] = __expf(pr[s16]-mx); sum += pr[s16]; }
    float inv = 1.f/sum;
    #pragma unroll
    for (int s16 = 0; s16 < 16; ++s16) pr[s16] *= inv;
    __syncthreads();   // all q/k reads done; QB reusable as AO
    float ov[16];
    #pragma unroll
    for (int d = 0; d < 16; ++d) ov[d] = 0.f;
    #pragma unroll
    for (int s16 = 0; s16 < 16; ++s16){
      float vv[16];
      ld16bf(VB + (win*16+s16)*136 + head*16, vv);
      #pragma unroll
      for (int d = 0; d < 16; ++d) ov[d] = fmaf(pr[s16], vv[d], ov[d]);
    }
    unsigned short* dst = QB + (win*16+tq)*136 + head*16;
    uint4 w0, w1;
    w0.x = pk2(ov[0],ov[1]);   w0.y = pk2(ov[2],ov[3]);
    w0.z = pk2(ov[4],ov[5]);   w0.w = pk2(ov[6],ov[7]);
    w1.x = pk2(ov[8],ov[9]);   w1.y = pk2(ov[10],ov[11]);
    w1.z = pk2(ov[12],ov[13]); w1.w = pk2(ov[14],ov[15]);
    *(uint4*)dst = w0;
    *(uint4*)(dst+8) = w1;
  }
  // proj
  f32x4 acc[2][2];
  #pragma unroll
  for (int i=0;i<2;++i)
    #pragma unroll
    for (int j=0;j<2;++j){ f32x4 z={0.f,0.f,0.f,0.f}; acc[i][j]=z; }
  for (int kc = 0; kc < 2; ++kc){
    __syncthreads();
    {
      int o = t >> 1, k0 = (t & 1) << 5;
      const unsigned short* src = Wproj + (size_t)o*128 + kc*64 + k0;
      unsigned short* dst = As + o*72 + k0;
      #pragma unroll
      for (int j = 0; j < 4; ++j) *(uint4*)(dst + j*8) = *(const uint4*)(src + j*8);
    }
    __syncthreads();
    #pragma unroll
    for (int ks = 0; ks < 2; ++ks){
      bf16x8 af[2], bfv[2];
      #pragma unroll
      for (int i=0;i<2;++i) af[i] = *(const bf16x8*)(As + (wv*32 + i*16 + l15)*72 + ks*32 + quad*8);
      #pragma unroll
      for (int j=0;j<2;++j) bfv[j] = *(const bf16x8*)(QB + (j*16 + l15)*136 + kc*64 + ks*32 + quad*8);
      #pragma unroll
      for (int i=0;i<2;++i)
        #pragma unroll
        for (int j=0;j<2;++j)
          acc[i][j] = __builtin_amdgcn_mfma_f32_16x16x32_bf16(af[i], bfv[j], acc[i][j], 0,0,0);
    }
  }
  __syncthreads();
  #pragma unroll
  for (int i = 0; i < 2; ++i){
    int o = wv*32 + i*16 + (quad<<2);
    float4 bv = *(const float4*)(bproj + o);
    #pragma unroll
    for (int j = 0; j < 2; ++j){
      int px = j*16 + l15;
      float v0=acc[i][j][0]+bv.x, v1=acc[i][j][1]+bv.y, v2=acc[i][j][2]+bv.z, v3=acc[i][j][3]+bv.w;
      float4 rv = *(const float4*)(XR + ((size_t)(p0+px))*128 + o);
      v0+=rv.x; v1+=rv.y; v2+=rv.z; v3+=rv.w;
      *(float4*)(OT + px*136 + o) = make_float4(v0,v1,v2,v3);
    }
  }
  __syncthreads();
  {
    int px = t >> 3, c0 = (t & 7) << 4;
    float* dst = XR + ((size_t)(p0+px))*128 + c0;
    const float* src = OT + px*136 + c0;
    #pragma unroll
    for (int gi = 0; gi < 4; ++gi){
      float4 v = *(const float4*)(src + gi*4);
      *(float4*)(dst + gi*4) = v;
      atomicAdd(&sgS[(c0>>2)+gi],  v.x+v.y+v.z+v.w);
      atomicAdd(&sgSS[(c0>>2)+gi], v.x*v.x+v.y*v.y+v.z*v.z+v.w*v.w);
    }
  }
  __syncthreads();
  if (t < 32){
    atomicAdd(&SG3[(b*32+t)*2],   sgS[t]);
    atomicAdd(&SG3[(b*32+t)*2+1], sgSS[t]);
  }
}

// ---------------- S3: AdaGN -> mlp1(silu) -> mlp2 -> +x => XR, + SG4 stats ----------------
__global__ __launch_bounds__(256) void k_s3(
    float* __restrict__ XR,
    const float* __restrict__ SG3, float* __restrict__ SG4,
    const unsigned short* __restrict__ W1, const float* __restrict__ b1,
    const unsigned short* __restrict__ W2, const float* __restrict__ b2,
    const float* __restrict__ gnw, const float* __restrict__ gnb,
    const float* __restrict__ scsh)
{
  __shared__ __align__(16) unsigned short Xs[64*136];
  __shared__ __align__(16) char UN[45056];  // As1 17408 | Hs 9216 | As2 18432 ; OT overlays (34816)
  __shared__ float An[128], Bn[128];
  __shared__ float sgS[32], sgSS[32];
  unsigned short* As1 = (unsigned short*)UN;
  unsigned short* Hs  = (unsigned short*)(UN + 17408);
  unsigned short* As2 = (unsigned short*)(UN + 26624);
  float* OT = (float*)UN;
  int t = threadIdx.x;
  int p0 = blockIdx.x << 6;
  int b = p0 >> 14;
  if (t < 128){
    int g = t >> 2;
    float S = SG3[(b*32+g)*2], SS = SG3[(b*32+g)*2+1];
    float m = S*(1.f/65536.f);
    float r = rsqrtf(SS*(1.f/65536.f) - m*m + EPSV);
    float sc = 1.f + scsh[b*256 + t];
    float sh = scsh[b*256 + 128 + t];
    An[t] = r*gnw[t]*sc;
    Bn[t] = (gnb[t] - m*r*gnw[t])*sc + sh;
  }
  if (t < 32){ sgS[t]=0.f; sgSS[t]=0.f; }
  __syncthreads();
  {
    int px = t >> 2, c0 = (t & 3) << 5;
    const float* src = XR + ((size_t)(p0+px))*128 + c0;
    unsigned short* dst = Xs + px*136 + c0;
    #pragma unroll
    for (int j = 0; j < 4; ++j){
      float4 v0 = *(const float4*)(src + j*8);
      float4 v1 = *(const float4*)(src + j*8 + 4);
      int c = c0 + j*8;
      uint4 w;
      w.x = pk2(fmaf(v0.x,An[c+0],Bn[c+0]), fmaf(v0.y,An[c+1],Bn[c+1]));
      w.y = pk2(fmaf(v0.z,An[c+2],Bn[c+2]), fmaf(v0.w,An[c+3],Bn[c+3]));
      w.z = pk2(fmaf(v1.x,An[c+4],Bn[c+4]), fmaf(v1.y,An[c+5],Bn[c+5]));
      w.w = pk2(fmaf(v1.z,An[c+6],Bn[c+6]), fmaf(v1.w,An[c+7],Bn[c+7]));
      *(uint4*)(dst + j*8) = w;
    }
  }
  int lane = t & 63, wv = t >> 6, quad = lane >> 4, l15 = lane & 15;
  f32x4 acc2[2][4];
  #pragma unroll
  for (int i=0;i<2;++i)
    #pragma unroll
    for (int j=0;j<4;++j){ f32x4 z={0.f,0.f,0.f,0.f}; acc2[i][j]=z; }
  for (int hc = 0; hc < 8; ++hc){
    __syncthreads();
    {
      int hr = t >> 2, k0 = (t & 3) << 5;
      const unsigned short* src = W1 + (size_t)(hc*64+hr)*128 + k0;
      unsigned short* dst = As1 + hr*136 + k0;
      #pragma unroll
      for (int j = 0; j < 4; ++j) *(uint4*)(dst + j*8) = *(const uint4*)(src + j*8);
    }
    {
      int o = t >> 1, k0 = (t & 1) << 5;
      const unsigned short* src = W2 + (size_t)o*512 + hc*64 + k0;
      unsigned short* dst = As2 + o*72 + k0;
      #pragma unroll
      for (int j = 0; j < 4; ++j) *(uint4*)(dst + j*8) = *(const uint4*)(src + j*8);
    }
    __syncthreads();
    // mfma1: 64h x 64px, wave: hb=(wv&1)*32, pxb=(wv>>1)*32
    {
      int hb = (wv & 1) << 5, pxb = (wv >> 1) << 5;
      f32x4 a1[2][2];
      #pragma unroll
      for (int i=0;i<2;++i)
        #pragma unroll
        for (int j=0;j<2;++j){ f32x4 z={0.f,0.f,0.f,0.f}; a1[i][j]=z; }
      #pragma unroll
      for (int s = 0; s < 4; ++s){
        bf16x8 af[2], bfv[2];
        #pragma unroll
        for (int i=0;i<2;++i) af[i] = *(const bf16x8*)(As1 + (hb + i*16 + l15)*136 + s*32 + quad*8);
        #pragma unroll
        for (int j=0;j<2;++j) bfv[j] = *(const bf16x8*)(Xs + (pxb + j*16 + l15)*136 + s*32 + quad*8);
        #pragma unroll
        for (int i=0;i<2;++i)
          #pragma unroll
          for (int j=0;j<2;++j)
            a1[i][j] = __builtin_amdgcn_mfma_f32_16x16x32_bf16(af[i], bfv[j], a1[i][j], 0,0,0);
      }
      // silu + bias -> Hs[px][h_local]
      #pragma unroll
      for (int i = 0; i < 2; ++i){
        int hl = hb + i*16 + (quad<<2);
        float4 bv = *(const float4*)(b1 + hc*64 + hl);
        #pragma unroll
        for (int j = 0; j < 2; ++j){
          int px = pxb + j*16 + l15;
          float v0=a1[i][j][0]+bv.x, v1=a1[i][j][1]+bv.y, v2=a1[i][j][2]+bv.z, v3=a1[i][j][3]+bv.w;
          v0*=sigmoidf_(v0); v1*=sigmoidf_(v1); v2*=sigmoidf_(v2); v3*=sigmoidf_(v3);
          *(unsigned int*)(Hs + px*72 + hl)     = pk2(v0, v1);
          *(unsigned int*)(Hs + px*72 + hl + 2) = pk2(v2, v3);
        }
      }
    }
    __syncthreads();
    // mfma2: 128o x 64px, wave: ob = wv*32
    {
      int ob = wv << 5;
      #pragma unroll
      for (int s = 0; s < 2; ++s){
        bf16x8 af[2], bfv[4];
        #pragma unroll
        for (int i=0;i<2;++i) af[i] = *(const bf16x8*)(As2 + (ob + i*16 + l15)*72 + s*32 + quad*8);
        #pragma unroll
        for (int j=0;j<4;++j) bfv[j] = *(const bf16x8*)(Hs + (j*16 + l15)*72 + s*32 + quad*8);
        #pragma unroll
        for (int i=0;i<2;++i)
          #pragma unroll
          for (int j=0;j<4;++j)
            acc2[i][j] = __builtin_amdgcn_mfma_f32_16x16x32_bf16(af[i], bfv[j], acc2[i][j], 0,0,0);
      }
    }
  }
  __syncthreads();
  #pragma unroll
  for (int i = 0; i < 2; ++i){
    int o = (wv<<5) + i*16 + (quad<<2);
    float4 bv = *(const float4*)(b2 + o);
    #pragma unroll
    for (int j = 0; j < 4; ++j){
      int px = j*16 + l15;
      float v0=acc2[i][j][0]+bv.x, v1=acc2[i][j][1]+bv.y, v2=acc2[i][j][2]+bv.z, v3=acc2[i][j][3]+bv.w;
      float4 rv = *(const float4*)(XR + ((size_t)(p0+px))*128 + o);
      v0+=rv.x; v1+=rv.y; v2+=rv.z; v3+=rv.w;
      *(float4*)(OT + px*136 + o) = make_float4(v0,v1,v2,v3);
    }
  }
  __syncthreads();
  {
    int px = t >> 2, c0 = (t & 3) << 5;
    float* dst = XR + ((size_t)(p0+px))*128 + c0;
    const float* src = OT + px*136 + c0;
    #pragma unroll
    for (int gi = 0; gi < 8; ++gi){
      float4 v = *(const float4*)(src + gi*4);
      *(float4*)(dst + gi*4) = v;
      atomicAdd(&sgS[(c0>>2)+gi],  v.x+v.y+v.z+v.w);
      atomicAdd(&sgSS[(c0>>2)+gi], v.x*v.x+v.y*v.y+v.z*v.z+v.w*v.w);
    }
  }
  __syncthreads();
  if (t < 32){
    atomicAdd(&SG4[(b*32+t)*2],   sgS[t]);
    atomicAdd(&SG4[(b*32+t)*2+1], sgSS[t]);
  }
}

// ---------------- k_dw: GN -> dw3x3 -> +b -> silu, XR [p'][128] -> DWO bf16 [p'][128] ----------------
__global__ __launch_bounds__(256) void k_dw(
    const float* __restrict__ XR, const float* __restrict__ SG4,
    const float* __restrict__ gnw, const float* __restrict__ gnb,
    const float* __restrict__ dww, const float* __restrict__ dwb,
    unsigned short* __restrict__ DWO)
{
  __shared__ float wt[9*128];
  __shared__ float An[128], Bn[128];
  int t = threadIdx.x;
  int p0 = blockIdx.x << 6;
  int b = p0 >> 14;
  int win0 = (p0 >> 4) & 1023;
  int wh = win0 >> 5, ww0 = win0 & 31;
  if (t < 128){
    int g = t >> 2;
    float S = SG4[(b*32+g)*2], SS = SG4[(b*32+g)*2+1];
    float m = S*(1.f/65536.f);
    float r = rsqrtf(SS*(1.f/65536.f) - m*m + EPSV);
    float A = r*gnw[t];
    An[t] = A;
    Bn[t] = gnb[t] - m*A;
  }
  for (int j = t; j < 1152; j += 256){ int c = j/9, tap = j%9; wt[tap*128 + c] = dww[j]; }
  __syncthreads();
  int pxl = t & 63, ck = t >> 6;
  int c0 = ck << 5;
  int wloc = pxl >> 4, ty = (pxl >> 2) & 3, tx = pxl & 3;
  int h = wh*4 + ty, w = (ww0 + wloc)*4 + tx;
  float acc[32];
  #pragma unroll
  for (int j = 0; j < 8; ++j){
    float4 bv = *(const float4*)(dwb + c0 + j*4);
    acc[j*4+0]=bv.x; acc[j*4+1]=bv.y; acc[j*4+2]=bv.z; acc[j*4+3]=bv.w;
  }
  #pragma unroll
  for (int dy = -1; dy <= 1; ++dy){
    int hh = h + dy;
    if (hh < 0 || hh > 127) continue;
    #pragma unroll
    for (int dx = -1; dx <= 1; ++dx){
      int wn = w + dx;
      if (wn < 0 || wn > 127) continue;
      int pn = b*IMGP + ((hh>>2)*32 + (wn>>2))*16 + (hh&3)*4 + (wn&3);
      const float* xp = XR + (size_t)pn*128 + c0;
      const float* wp = wt + ((dy+1)*3 + (dx+1))*128 + c0;
      #pragma unroll
      for (int j = 0; j < 8; ++j){
        float4 xv = *(const float4*)(xp + j*4);
        float4 wv = *(const float4*)(wp + j*4);
        int c = c0 + j*4;
        acc[j*4+0] = fmaf(wv.x, fmaf(An[c+0], xv.x, Bn[c+0]), acc[j*4+0]);
        acc[j*4+1] = fmaf(wv.y, fmaf(An[c+1], xv.y, Bn[c+1]), acc[j*4+1]);
        acc[j*4+2] = fmaf(wv.z, fmaf(An[c+2], xv.z, Bn[c+2]), acc[j*4+2]);
        acc[j*4+3] = fmaf(wv.w, fmaf(An[c+3], xv.w, Bn[c+3]), acc[j*4+3]);
      }
    }
  }
  unsigned short* dst = DWO + ((size_t)(p0+pxl))*128 + c0;
  #pragma unroll
  for (int j = 0; j < 4; ++j){
    float v0 = acc[j*8+0], v1 = acc[j*8+1], v2 = acc[j*8+2], v3 = acc[j*8+3];
    float v4 = acc[j*8+4], v5 = acc[j*8+5], v6 = acc[j*8+6], v7 = acc[j*8+7];
    v0*=sigmoidf_(v0); v1*=sigmoidf_(v1); v2*=sigmoidf_(v2); v3*=sigmoidf_(v3);
    v4*=sigmoidf_(v4); v5*=sigmoidf_(v5); v6*=sigmoidf_(v6); v7*=sigmoidf_(v7);
    uint4 wq;
    wq.x = pk2(v0,v1); wq.y = pk2(v2,v3); wq.z = pk2(v4,v5); wq.w = pk2(v6,v7);
    *(uint4*)(dst + j*8) = wq;
  }
}

// ---------------- S4: pw 1x1 over DWO -> +x => d_out [c][h][w] ----------------
__global__ __launch_bounds__(256) void k_s4(
    const unsigned short* __restrict__ DWO,
    const unsigned short* __restrict__ Wbf, const float* __restrict__ bias,
    const float* __restrict__ XR, float* __restrict__ out)
{
  __shared__ __align__(16) unsigned short Bs[64*136];
  __shared__ __align__(16) char UN[64*136*4];  // As [128][72] | OT [64][136] f32
  unsigned short* As = (unsigned short*)UN;
  float* OT = (float*)UN;
  int t = threadIdx.x;
  int p0 = blockIdx.x << 6;
  int b = p0 >> 14;
  int win0 = (p0 >> 4) & 1023;
  int wh = win0 >> 5, ww0 = win0 & 31;
  {
    int px = t >> 2, c0 = (t & 3) << 5;
    const unsigned short* src = DWO + ((size_t)(p0+px))*128 + c0;
    unsigned short* dst = Bs + px*136 + c0;
    #pragma unroll
    for (int j = 0; j < 4; ++j) *(uint4*)(dst + j*8) = *(const uint4*)(src + j*8);
  }
  f32x4 acc[2][4];
  #pragma unroll
  for (int i=0;i<2;++i)
    #pragma unroll
    for (int j=0;j<4;++j){ f32x4 z={0.f,0.f,0.f,0.f}; acc[i][j]=z; }
  int lane = t & 63, wv = t >> 6, quad = lane >> 4, l15 = lane & 15;
  for (int kc = 0; kc < 2; ++kc){
    __syncthreads();
    {
      int o = t >> 1, k0 = (t & 1) << 5;
      const unsigned short* src = Wbf + (size_t)o*128 + kc*64 + k0;
      unsigned short* dst = As + o*72 + k0;
      #pragma unroll
      for (int j = 0; j < 4; ++j) *(uint4*)(dst + j*8) = *(const uint4*)(src + j*8);
    }
    __syncthreads();
    #pragma unroll
    for (int s = 0; s < 2; ++s){
      bf16x8 af[2], bfv[4];
      #pragma unroll
      for (int i=0;i<2;++i) af[i] = *(const bf16x8*)(As + (wv*32 + i*16 + l15)*72 + s*32 + quad*8);
      #pragma unroll
      for (int j=0;j<4;++j) bfv[j] = *(const bf16x8*)(Bs + (j*16 + l15)*136 + kc*64 + s*32 + quad*8);
      #pragma unroll
      for (int i=0;i<2;++i)
        #pragma unroll
        for (int j=0;j<4;++j)
          acc[i][j] = __builtin_amdgcn_mfma_f32_16x16x32_bf16(af[i], bfv[j], acc[i][j], 0,0,0);
    }
  }
  __syncthreads();
  #pragma unroll
  for (int i = 0; i < 2; ++i){
    int o = (wv<<5) + i*16 + (quad<<2);
    float4 bv = *(const float4*)(bias + o);
    #pragma unroll
    for (int j = 0; j < 4; ++j){
      int px = j*16 + l15;
      float v0=acc[i][j][0]+bv.x, v1=acc[i][j][1]+bv.y, v2=acc[i][j][2]+bv.z, v3=acc[i][j][3]+bv.w;
      float4 rv = *(const float4*)(XR + ((size_t)(p0+px))*128 + o);
      v0+=rv.x; v1+=rv.y; v2+=rv.z; v3+=rv.w;
      *(float4*)(OT + px*136 + o) = make_float4(v0,v1,v2,v3);
    }
  }
  __syncthreads();
  // fat write to out [c][h][w]: item = (c, ty), 16 contiguous w
  #pragma unroll
  for (int it = 0; it < 2; ++it){
    int item = t + (it << 8);
    int c = item >> 2, ty = item & 3;
    float vbuf[16];
    #pragma unroll
    for (int wl = 0; wl < 4; ++wl)
      #pragma unroll
      for (int tx = 0; tx < 4; ++tx)
        vbuf[wl*4+tx] = OT[(wl*16 + ty*4 + tx)*136 + c];
    float* dst = out + ((size_t)(b*128 + c))*IMGP + (wh*4+ty)*128 + ww0*4;
    #pragma unroll
    for (int j = 0; j < 4; ++j)
      *(float4*)(dst + j*4) = make_float4(vbuf[j*4], vbuf[j*4+1], vbuf[j*4+2], vbuf[j*4+3]);
  }
}

extern "C" void kernel_launch(void* const* d_in, const int* in_sizes, int n_in,
                              void* d_out, int out_size, void* d_ws, size_t ws_size,
                              hipStream_t stream)
{
  const float* x0   = (const float*)d_in[0];
  const float* temb = (const float*)d_in[1];
  const float* gn1w = (const float*)d_in[2];
  const float* gn1b = (const float*)d_in[3];
  const float* t1w1 = (const float*)d_in[4];
  const float* t1b1 = (const float*)d_in[5];
  const float* t1w2 = (const float*)d_in[6];
  const float* t1b2 = (const float*)d_in[7];
  const float* specw= (const float*)d_in[8];
  const float* specb= (const float*)d_in[9];
  const float* modew= (const float*)d_in[10];
  const float* gn2w = (const float*)d_in[11];
  const float* gn2b = (const float*)d_in[12];
  const float* t2w1 = (const float*)d_in[13];
  const float* t2b1 = (const float*)d_in[14];
  const float* t2w2 = (const float*)d_in[15];
  const float* t2b2 = (const float*)d_in[16];
  const float* qkvw = (const float*)d_in[17];
  const float* qkvb = (const float*)d_in[18];
  const float* projw= (const float*)d_in[19];
  const float* projb= (const float*)d_in[20];
  const float* relb = (const float*)d_in[21];
  const float* gn3w = (const float*)d_in[22];
  const float* gn3b = (const float*)d_in[23];
  const float* t3w1 = (const float*)d_in[24];
  const float* t3b1 = (const float*)d_in[25];
  const float* t3w2 = (const float*)d_in[26];
  const float* t3b2 = (const float*)d_in[27];
  const float* mlpw1= (const float*)d_in[28];
  const float* mlpb1= (const float*)d_in[29];
  const float* mlpw2= (const float*)d_in[30];
  const float* mlpb2= (const float*)d_in[31];
  const float* sbgnw= (const float*)d_in[32];
  const float* sbgnb= (const float*)d_in[33];
  const float* dww  = (const float*)d_in[34];
  const float* dwb  = (const float*)d_in[35];
  const float* pww  = (const float*)d_in[36];
  const float* pwb  = (const float*)d_in[37];
  float* out = (float*)d_out;

  char* ws = (char*)d_ws;
  float* SC  = (float*)ws;                          // 3*2048 floats = 24KB
  float* SG  = (float*)(ws + 32768);                // 4*512 floats = 8KB
  float* SG1 = SG, *SG2 = SG+512, *SG3 = SG+1024, *SG4 = SG+1536;
  unsigned short* WBF = (unsigned short*)(ws + 65536);  // 458752 B
  unsigned short* Wspec = WBF;
  unsigned short* Wqkv  = WBF + 16384;
  unsigned short* Wproj = WBF + 65536;
  unsigned short* Wmlp1 = WBF + 81920;
  unsigned short* Wmlp2 = WBF + 147456;
  unsigned short* Wpw   = WBF + 212992;
  float* X0T = (float*)(ws + (1u<<20));                              // 64 MiB
  float* XR  = (float*)(ws + (1u<<20) + ((size_t)64<<20));           // 64 MiB
  unsigned short* DWO = (unsigned short*)(ws + (1u<<20) + ((size_t)128<<20)); // 32 MiB

  hipMemsetAsync(SG, 0, 4*512*sizeof(float), stream);

  k_prep<<<896, 256, 0, stream>>>(specw, qkvw, projw, mlpw1, mlpw2, pww, WBF);
  k_time_mlp<<<dim3(8,3), 256, 0, stream>>>(temb,
      t1w1,t1b1,t1w2,t1b2, t2w1,t2b1,t2w2,t2b2, t3w1,t3b1,t3w2,t3b2, SC);
  k_pre<<<2048, 256, 0, stream>>>(x0, X0T, SG1);
  k_s1<<<2048, 256, 0, stream>>>(X0T, SG1, SG2, Wspec, specb,
      gn1w, gn1b, SC + 0, modew, XR);
  k_s2<<<4096, 256, 0, stream>>>(XR, SG2, SG3, Wqkv, qkvb, Wproj, projb,
      relb, gn2w, gn2b, SC + 2048);
  k_s3<<<2048, 256, 0, stream>>>(XR, SG3, SG4, Wmlp1, mlpb1, Wmlp2, mlpb2,
      gn3w, gn3b, SC + 4096);
  k_dw<<<2048, 256, 0, stream>>>(XR, SG4, sbgnw, sbgnb, dww, dwb, DWO);
  k_s4<<<2048, 256, 0, stream>>>(DWO, Wpw, pwb, XR, out);
}

// Round 4
// 705.860 us; speedup vs baseline: 1.1483x; 1.1483x over previous
//
#include <hip/hip_runtime.h>

#define IMGP 16384
#define BATCH 8
#define EPSV 1e-5f

typedef short bf16x8 __attribute__((ext_vector_type(8)));
typedef float f32x4 __attribute__((ext_vector_type(4)));

__device__ __forceinline__ float bf2f(unsigned short u){
  union { unsigned int i; float f; } v; v.i = ((unsigned int)u) << 16; return v.f;
}
__device__ __forceinline__ unsigned short f2bf(float f){
  union { float f; unsigned int i; } v; v.f = f;
  unsigned int r = v.i + 0x7FFFu + ((v.i >> 16) & 1u);
  return (unsigned short)(r >> 16);
}
__device__ __forceinline__ unsigned int pk2(float a, float b){
  return (unsigned int)f2bf(a) | ((unsigned int)f2bf(b) << 16);
}
__device__ __forceinline__ float sigmoidf_(float x){ return 1.f/(1.f + __expf(-x)); }

__device__ __forceinline__ void ub8(uint4 u, float* f){
  f[0]=bf2f((unsigned short)(u.x&0xffff)); f[1]=bf2f((unsigned short)(u.x>>16));
  f[2]=bf2f((unsigned short)(u.y&0xffff)); f[3]=bf2f((unsigned short)(u.y>>16));
  f[4]=bf2f((unsigned short)(u.z&0xffff)); f[5]=bf2f((unsigned short)(u.z>>16));
  f[6]=bf2f((unsigned short)(u.w&0xffff)); f[7]=bf2f((unsigned short)(u.w>>16));
}
__device__ __forceinline__ uint4 pb8(const float* f){
  uint4 r; r.x = pk2(f[0],f[1]); r.y = pk2(f[2],f[3]);
  r.z = pk2(f[4],f[5]); r.w = pk2(f[6],f[7]); return r;
}
__device__ __forceinline__ void ld16lds(const unsigned short* p, float* f){
  uint4 u0 = *(const uint4*)p; uint4 u1 = *(const uint4*)(p+8);
  ub8(u0, f); ub8(u1, f+8);
}

// ---------------- weight prep fp32->bf16 ----------------
__global__ __launch_bounds__(256) void k_prep(
    const float* __restrict__ a0, const float* __restrict__ a1,
    const float* __restrict__ a2, const float* __restrict__ a3,
    const float* __restrict__ a4, const float* __restrict__ a5,
    unsigned short* __restrict__ dst)
{
  int i = blockIdx.x*256 + threadIdx.x;
  if (i >= 229376) return;
  float v;
  if (i < 16384) v = a0[i];
  else if (i < 65536) v = a1[i-16384];
  else if (i < 81920) v = a2[i-65536];
  else if (i < 147456) v = a3[i-81920];
  else if (i < 212992) v = a4[i-147456];
  else v = a5[i-212992];
  dst[i] = f2bf(v);
}

// ---------------- time MLP (3 stages) ----------------
__global__ __launch_bounds__(256) void k_tmlp(
    const float* __restrict__ temb,
    const float* __restrict__ w1a, const float* __restrict__ b1a,
    const float* __restrict__ w2a, const float* __restrict__ b2a,
    const float* __restrict__ w1b, const float* __restrict__ b1b,
    const float* __restrict__ w2b, const float* __restrict__ b2b,
    const float* __restrict__ w1c, const float* __restrict__ b1c,
    const float* __restrict__ w2c, const float* __restrict__ b2c,
    float* __restrict__ scsh)
{
  int b = blockIdx.x, s = blockIdx.y, t = threadIdx.x;
  const float* w1 = (s==0)? w1a : ((s==1)? w1b : w1c);
  const float* b1 = (s==0)? b1a : ((s==1)? b1b : b1c);
  const float* w2 = (s==0)? w2a : ((s==1)? w2b : w2c);
  const float* b2 = (s==0)? b2a : ((s==1)? b2b : b2c);
  __shared__ float te[256];
  __shared__ float hb[512];
  te[t] = temb[b*256 + t];
  __syncthreads();
  for (int k = t; k < 512; k += 256){
    float acc = b1[k];
    const float* wr = w1 + (size_t)k*256;
    for (int j = 0; j < 256; j += 4){
      float4 w = *(const float4*)(wr + j);
      acc += w.x*te[j] + w.y*te[j+1] + w.z*te[j+2] + w.w*te[j+3];
    }
    hb[k] = acc * sigmoidf_(acc);
  }
  __syncthreads();
  {
    float acc = b2[t];
    const float* wr = w2 + (size_t)t*512;
    for (int j = 0; j < 512; j += 4){
      float4 w = *(const float4*)(wr + j);
      acc += w.x*hb[j] + w.y*hb[j+1] + w.z*hb[j+2] + w.w*hb[j+3];
    }
    scsh[(size_t)(s*BATCH + b)*256 + t] = acc;
  }
}

// ---------------- k_pre: x0 [c][p] fp32 -> X0b [p][c] bf16 + SG1 ----------------
__global__ __launch_bounds__(256) void k_pre(
    const float* __restrict__ x0, unsigned short* __restrict__ X0b, float* __restrict__ SG1)
{
  __shared__ __align__(16) unsigned short T[64*136];
  __shared__ float sgS[32], sgSS[32];
  int t = threadIdx.x;
  int p0 = blockIdx.x << 6;
  int b = p0 >> 14;
  int hw0 = p0 & 16383;
  if (t < 32){ sgS[t]=0.f; sgSS[t]=0.f; }
  __syncthreads();
  {
    int c = t >> 1, q = t & 1;
    const float* src = x0 + (size_t)(b*128 + c)*IMGP + hw0 + q*32;
    float s = 0.f, ss = 0.f;
    #pragma unroll
    for (int i = 0; i < 8; ++i){
      float4 v = *(const float4*)(src + i*4);
      int px = q*32 + i*4;
      T[(px+0)*136 + c] = f2bf(v.x);
      T[(px+1)*136 + c] = f2bf(v.y);
      T[(px+2)*136 + c] = f2bf(v.z);
      T[(px+3)*136 + c] = f2bf(v.w);
      s  += v.x + v.y + v.z + v.w;
      ss += v.x*v.x + v.y*v.y + v.z*v.z + v.w*v.w;
    }
    atomicAdd(&sgS[c>>2], s);
    atomicAdd(&sgSS[c>>2], ss);
  }
  __syncthreads();
  {
    int px = t >> 2, c0 = (t & 3) << 5;
    unsigned short* dst = X0b + (size_t)(p0+px)*128 + c0;
    const unsigned short* srcT = T + px*136 + c0;
    #pragma unroll
    for (int g = 0; g < 4; ++g) *(uint4*)(dst + g*8) = *(const uint4*)(srcT + g*8);
  }
  __syncthreads();
  if (t < 32){
    atomicAdd(&SG1[(b*32+t)*2],   sgS[t]);
    atomicAdd(&SG1[(b*32+t)*2+1], sgSS[t]);
  }
}

// ---------------- k_s1: AdaGN*sig(modew) -> spec 1x1 -> silu -> +X0b => XRb + SG2 ----------------
__global__ __launch_bounds__(256) void k_s1(
    const unsigned short* __restrict__ X0b,
    const float* __restrict__ SG1, float* __restrict__ SG2,
    const unsigned short* __restrict__ Wbf, const float* __restrict__ bias,
    const float* __restrict__ gnw, const float* __restrict__ gnb,
    const float* __restrict__ scsh, const float* __restrict__ modew,
    unsigned short* __restrict__ XRb)
{
  __shared__ __align__(16) char UN[36864];  // As 18432 | Bs 18432 ; OT [128][136] overlay
  __shared__ float An[128], Bn[128];
  __shared__ float sgS[32], sgSS[32];
  unsigned short* As = (unsigned short*)UN;
  unsigned short* Bs = (unsigned short*)(UN + 18432);
  unsigned short* OT = (unsigned short*)UN;
  int t = threadIdx.x;
  int p0 = blockIdx.x << 7;
  int b = p0 >> 14;
  if (t < 128){
    int g = t >> 2;
    float S = SG1[(b*32+g)*2], SS = SG1[(b*32+g)*2+1];
    float m = S*(1.f/65536.f);
    float r = rsqrtf(SS*(1.f/65536.f) - m*m + EPSV);
    float sc = 1.f + scsh[b*256 + t];
    float sh = scsh[b*256 + 128 + t];
    float a = r*gnw[t]*sc;
    float bb = (gnb[t] - m*r*gnw[t])*sc + sh;
    float sg = sigmoidf_(modew[t]); a *= sg; bb *= sg;
    An[t] = a; Bn[t] = bb;
  }
  if (t < 32){ sgS[t]=0.f; sgSS[t]=0.f; }
  __syncthreads();
  int lane = t & 63, wv = t >> 6, quad = lane >> 4, l15 = lane & 15;
  int wo = (wv & 1) << 6, wp = (wv >> 1) << 6;
  f32x4 acc[4][4];
  #pragma unroll
  for (int i=0;i<4;++i)
    #pragma unroll
    for (int j=0;j<4;++j){ f32x4 z={0.f,0.f,0.f,0.f}; acc[i][j]=z; }
  for (int kc = 0; kc < 2; ++kc){
    if (kc) __syncthreads();
    { int o = t >> 1, kh = (t & 1) << 5;
      const unsigned short* src = Wbf + o*128 + kc*64 + kh;
      unsigned short* dst = As + o*72 + kh;
      #pragma unroll
      for (int j = 0; j < 4; ++j) *(uint4*)(dst + j*8) = *(const uint4*)(src + j*8);
    }
    { int px = t >> 1, kh = (t & 1) << 5;
      const unsigned short* src = X0b + (size_t)(p0+px)*128 + kc*64 + kh;
      unsigned short* dst = Bs + px*72 + kh;
      #pragma unroll
      for (int j = 0; j < 4; ++j){
        uint4 u = *(const uint4*)(src + j*8);
        float f[8], g[8];
        ub8(u, f);
        int c = kc*64 + kh + j*8;
        #pragma unroll
        for (int e = 0; e < 8; ++e) g[e] = fmaf(f[e], An[c+e], Bn[c+e]);
        *(uint4*)(dst + j*8) = pb8(g);
      }
    }
    __syncthreads();
    #pragma unroll
    for (int s = 0; s < 2; ++s){
      bf16x8 af[4], bfv[4];
      #pragma unroll
      for (int i=0;i<4;++i) af[i]  = *(const bf16x8*)(As + (wo+i*16+l15)*72 + s*32 + quad*8);
      #pragma unroll
      for (int j=0;j<4;++j) bfv[j] = *(const bf16x8*)(Bs + (wp+j*16+l15)*72 + s*32 + quad*8);
      #pragma unroll
      for (int i=0;i<4;++i)
        #pragma unroll
        for (int j=0;j<4;++j)
          acc[i][j] = __builtin_amdgcn_mfma_f32_16x16x32_bf16(af[i], bfv[j], acc[i][j], 0,0,0);
    }
  }
  __syncthreads();
  #pragma unroll
  for (int i = 0; i < 4; ++i){
    int o = wo + i*16 + (quad<<2);
    float4 bv = *(const float4*)(bias + o);
    #pragma unroll
    for (int j = 0; j < 4; ++j){
      int px = wp + j*16 + l15;
      float v0=acc[i][j][0]+bv.x, v1=acc[i][j][1]+bv.y, v2=acc[i][j][2]+bv.z, v3=acc[i][j][3]+bv.w;
      v0*=sigmoidf_(v0); v1*=sigmoidf_(v1); v2*=sigmoidf_(v2); v3*=sigmoidf_(v3);
      uint2 w; w.x = pk2(v0,v1); w.y = pk2(v2,v3);
      *(uint2*)(OT + px*136 + o) = w;
    }
  }
  __syncthreads();
  {
    int px = t >> 1, c0 = (t & 1) << 6;
    const unsigned short* rsrc = X0b + (size_t)(p0+px)*128 + c0;
    unsigned short* dst = XRb + (size_t)(p0+px)*128 + c0;
    #pragma unroll
    for (int g = 0; g < 8; ++g){
      uint4 hu = *(const uint4*)(OT + px*136 + c0 + g*8);
      uint4 ru = *(const uint4*)(rsrc + g*8);
      float hf[8], rf[8], v[8];
      ub8(hu, hf); ub8(ru, rf);
      #pragma unroll
      for (int e = 0; e < 8; ++e) v[e] = hf[e] + rf[e];
      float slo = v[0]+v[1]+v[2]+v[3], shi = v[4]+v[5]+v[6]+v[7];
      float qlo = v[0]*v[0]+v[1]*v[1]+v[2]*v[2]+v[3]*v[3];
      float qhi = v[4]*v[4]+v[5]*v[5]+v[6]*v[6]+v[7]*v[7];
      int gb = (c0 + g*8) >> 2;
      atomicAdd(&sgS[gb], slo);  atomicAdd(&sgS[gb+1], shi);
      atomicAdd(&sgSS[gb], qlo); atomicAdd(&sgSS[gb+1], qhi);
      *(uint4*)(dst + g*8) = pb8(v);
    }
  }
  __syncthreads();
  if (t < 32){
    atomicAdd(&SG2[(b*32+t)*2],   sgS[t]);
    atomicAdd(&SG2[(b*32+t)*2+1], sgSS[t]);
  }
}

// ---------------- k_qkv: AdaGN -> qkv GEMM chunk (blockIdx.y = q/k/v) => QKV bf16 [p][384] ----------------
__global__ __launch_bounds__(256) void k_qkv(
    const unsigned short* __restrict__ XRb,
    const float* __restrict__ SG2,
    const unsigned short* __restrict__ Wq, const float* __restrict__ bq,
    const float* __restrict__ gnw, const float* __restrict__ gnb,
    const float* __restrict__ scsh,
    unsigned short* __restrict__ QKV)
{
  __shared__ __align__(16) char UN[36864];
  __shared__ float An[128], Bn[128];
  unsigned short* As = (unsigned short*)UN;
  unsigned short* Bs = (unsigned short*)(UN + 18432);
  unsigned short* OT = (unsigned short*)UN;
  int t = threadIdx.x;
  int p0 = blockIdx.x << 7;
  int b = p0 >> 14;
  int sel = blockIdx.y;
  if (t < 128){
    int g = t >> 2;
    float S = SG2[(b*32+g)*2], SS = SG2[(b*32+g)*2+1];
    float m = S*(1.f/65536.f);
    float r = rsqrtf(SS*(1.f/65536.f) - m*m + EPSV);
    float sc = 1.f + scsh[b*256 + t];
    float sh = scsh[b*256 + 128 + t];
    An[t] = r*gnw[t]*sc;
    Bn[t] = (gnb[t] - m*r*gnw[t])*sc + sh;
  }
  __syncthreads();
  int lane = t & 63, wv = t >> 6, quad = lane >> 4, l15 = lane & 15;
  int wo = (wv & 1) << 6, wp = (wv >> 1) << 6;
  f32x4 acc[4][4];
  #pragma unroll
  for (int i=0;i<4;++i)
    #pragma unroll
    for (int j=0;j<4;++j){ f32x4 z={0.f,0.f,0.f,0.f}; acc[i][j]=z; }
  for (int kc = 0; kc < 2; ++kc){
    if (kc) __syncthreads();
    { int o = t >> 1, kh = (t & 1) << 5;
      const unsigned short* src = Wq + (size_t)sel*16384 + o*128 + kc*64 + kh;
      unsigned short* dst = As + o*72 + kh;
      #pragma unroll
      for (int j = 0; j < 4; ++j) *(uint4*)(dst + j*8) = *(const uint4*)(src + j*8);
    }
    { int px = t >> 1, kh = (t & 1) << 5;
      const unsigned short* src = XRb + (size_t)(p0+px)*128 + kc*64 + kh;
      unsigned short* dst = Bs + px*72 + kh;
      #pragma unroll
      for (int j = 0; j < 4; ++j){
        uint4 u = *(const uint4*)(src + j*8);
        float f[8], g[8];
        ub8(u, f);
        int c = kc*64 + kh + j*8;
        #pragma unroll
        for (int e = 0; e < 8; ++e) g[e] = fmaf(f[e], An[c+e], Bn[c+e]);
        *(uint4*)(dst + j*8) = pb8(g);
      }
    }
    __syncthreads();
    #pragma unroll
    for (int s = 0; s < 2; ++s){
      bf16x8 af[4], bfv[4];
      #pragma unroll
      for (int i=0;i<4;++i) af[i]  = *(const bf16x8*)(As + (wo+i*16+l15)*72 + s*32 + quad*8);
      #pragma unroll
      for (int j=0;j<4;++j) bfv[j] = *(const bf16x8*)(Bs + (wp+j*16+l15)*72 + s*32 + quad*8);
      #pragma unroll
      for (int i=0;i<4;++i)
        #pragma unroll
        for (int j=0;j<4;++j)
          acc[i][j] = __builtin_amdgcn_mfma_f32_16x16x32_bf16(af[i], bfv[j], acc[i][j], 0,0,0);
    }
  }
  __syncthreads();
  #pragma unroll
  for (int i = 0; i < 4; ++i){
    int o = wo + i*16 + (quad<<2);
    float4 bv = *(const float4*)(bq + sel*128 + o);
    #pragma unroll
    for (int j = 0; j < 4; ++j){
      int px = wp + j*16 + l15;
      uint2 w; w.x = pk2(acc[i][j][0]+bv.x, acc[i][j][1]+bv.y);
      w.y = pk2(acc[i][j][2]+bv.z, acc[i][j][3]+bv.w);
      *(uint2*)(OT + px*136 + o) = w;
    }
  }
  __syncthreads();
  {
    int px = t >> 1, og = (t & 1) << 6;
    unsigned short* dst = QKV + (size_t)(p0+px)*384 + (sel << 7) + og;
    const unsigned short* src = OT + px*136 + og;
    #pragma unroll
    for (int g = 0; g < 8; ++g) *(uint4*)(dst + g*8) = *(const uint4*)(src + g*8);
  }
}

// ---------------- k_ap: window attention + proj -> +XRb => XRb + SG3 ----------------
__global__ __launch_bounds__(256) void k_ap(
    const unsigned short* __restrict__ QKV,
    const unsigned short* __restrict__ Wproj, const float* __restrict__ bproj,
    const float* __restrict__ relb,
    unsigned short* __restrict__ XRb, float* __restrict__ SG3)
{
  __shared__ __align__(16) unsigned short AOb[128*136];   // 34816 B; OT overlays
  __shared__ __align__(16) unsigned short UNQ[12288];     // QKVs 24576 B; As (18432) overlays
  __shared__ float relbs[392];
  __shared__ float sgS[32], sgSS[32];
  unsigned short* QKVs = UNQ;
  unsigned short* As = UNQ;
  int t = threadIdx.x;
  int blk = blockIdx.x;
  int b = blk >> 7;
  int rem = blk & 127;
  int h0 = (rem >> 2) << 2;
  int w0 = (rem & 3) << 5;
  int baseP = b*IMGP + h0*128 + w0;
  for (int j = t; j < 392; j += 256) relbs[j] = relb[j];
  if (t < 32){ sgS[t]=0.f; sgSS[t]=0.f; }
  // ---- attention over 8 windows, head-pairs ----
  for (int hb = 0; hb < 8; hb += 2){
    __syncthreads();
    #pragma unroll
    for (int pass = 0; pass < 6; ++pass){
      int u = t + (pass << 8);
      int sel = u >> 9;
      int r = u & 511;
      int hp = r >> 8;
      int pxh = r & 255;
      int pxl = pxh >> 1;
      int dh = (pxh & 1) << 3;
      int pg = baseP + ((pxl >> 5) << 7) + (pxl & 31);
      *(uint4*)(QKVs + (((sel*2+hp) << 7) + pxl)*16 + dh) =
        *(const uint4*)(QKV + (size_t)pg*384 + (sel << 7) + ((hb+hp) << 4) + dh);
    }
    __syncthreads();
    {
      int hp = t >> 7, win = (t >> 4) & 7, tq = t & 15;
      int head = hb + hp;
      int ty = tq >> 2, tx = tq & 3;
      int pq = (ty << 5) + (win << 2) + tx;
      float qv[16];
      ld16lds(QKVs + ((hp << 7) + pq)*16, qv);
      float pr[16]; float mx = -1e30f;
      #pragma unroll
      for (int s = 0; s < 16; ++s){
        int ps = ((s >> 2) << 5) + (win << 2) + (s & 3);
        float kv[16];
        ld16lds(QKVs + (((2+hp) << 7) + ps)*16, kv);
        float dot = 0.f;
        #pragma unroll
        for (int d = 0; d < 16; ++d) dot = fmaf(qv[d], kv[d], dot);
        int idx = (ty-(s>>2)+3)*7 + (tx-(s&3)+3);
        pr[s] = dot*0.25f + relbs[idx*8 + head];
        mx = fmaxf(mx, pr[s]);
      }
      float sum = 0.f;
      #pragma unroll
      for (int s = 0; s < 16; ++s){ pr[s] = __expf(pr[s]-mx); sum += pr[s]; }
      float inv = 1.f/sum;
      float ov[16];
      #pragma unroll
      for (int d = 0; d < 16; ++d) ov[d] = 0.f;
      #pragma unroll
      for (int s = 0; s < 16; ++s){
        int ps = ((s >> 2) << 5) + (win << 2) + (s & 3);
        float vv[16];
        ld16lds(QKVs + (((4+hp) << 7) + ps)*16, vv);
        #pragma unroll
        for (int d = 0; d < 16; ++d) ov[d] = fmaf(pr[s], vv[d], ov[d]);
      }
      #pragma unroll
      for (int d = 0; d < 16; ++d) ov[d] *= inv;
      unsigned short* dst = AOb + pq*136 + (head << 4);
      *(uint4*)dst     = pb8(ov);
      *(uint4*)(dst+8) = pb8(ov+8);
    }
  }
  // ---- proj GEMM (Bs = AOb) ----
  int lane = t & 63, wv = t >> 6, quad = lane >> 4, l15 = lane & 15;
  int wo = (wv & 1) << 6, wp = (wv >> 1) << 6;
  f32x4 acc[4][4];
  #pragma unroll
  for (int i=0;i<4;++i)
    #pragma unroll
    for (int j=0;j<4;++j){ f32x4 z={0.f,0.f,0.f,0.f}; acc[i][j]=z; }
  for (int kc = 0; kc < 2; ++kc){
    __syncthreads();
    { int o = t >> 1, kh = (t & 1) << 5;
      const unsigned short* src = Wproj + o*128 + kc*64 + kh;
      unsigned short* dst = As + o*72 + kh;
      #pragma unroll
      for (int j = 0; j < 4; ++j) *(uint4*)(dst + j*8) = *(const uint4*)(src + j*8);
    }
    __syncthreads();
    #pragma unroll
    for (int s = 0; s < 2; ++s){
      bf16x8 af[4], bfv[4];
      #pragma unroll
      for (int i=0;i<4;++i) af[i]  = *(const bf16x8*)(As + (wo+i*16+l15)*72 + s*32 + quad*8);
      #pragma unroll
      for (int j=0;j<4;++j) bfv[j] = *(const bf16x8*)(AOb + (wp+j*16+l15)*136 + kc*64 + s*32 + quad*8);
      #pragma unroll
      for (int i=0;i<4;++i)
        #pragma unroll
        for (int j=0;j<4;++j)
          acc[i][j] = __builtin_amdgcn_mfma_f32_16x16x32_bf16(af[i], bfv[j], acc[i][j], 0,0,0);
    }
  }
  __syncthreads();
  #pragma unroll
  for (int i = 0; i < 4; ++i){
    int o = wo + i*16 + (quad<<2);
    float4 bv = *(const float4*)(bproj + o);
    #pragma unroll
    for (int j = 0; j < 4; ++j){
      int px = wp + j*16 + l15;
      uint2 w; w.x = pk2(acc[i][j][0]+bv.x, acc[i][j][1]+bv.y);
      w.y = pk2(acc[i][j][2]+bv.z, acc[i][j][3]+bv.w);
      *(uint2*)(AOb + px*136 + o) = w;
    }
  }
  __syncthreads();
  {
    int px = t >> 1, c0 = (t & 1) << 6;
    int pg = baseP + ((px >> 5) << 7) + (px & 31);
    unsigned short* dst = XRb + (size_t)pg*128 + c0;
    #pragma unroll
    for (int g = 0; g < 8; ++g){
      uint4 hu = *(const uint4*)(AOb + px*136 + c0 + g*8);
      uint4 ru = *(const uint4*)(dst + g*8);
      float hf[8], rf[8], v[8];
      ub8(hu, hf); ub8(ru, rf);
      #pragma unroll
      for (int e = 0; e < 8; ++e) v[e] = hf[e] + rf[e];
      float slo = v[0]+v[1]+v[2]+v[3], shi = v[4]+v[5]+v[6]+v[7];
      float qlo = v[0]*v[0]+v[1]*v[1]+v[2]*v[2]+v[3]*v[3];
      float qhi = v[4]*v[4]+v[5]*v[5]+v[6]*v[6]+v[7]*v[7];
      int gb = (c0 + g*8) >> 2;
      atomicAdd(&sgS[gb], slo);  atomicAdd(&sgS[gb+1], shi);
      atomicAdd(&sgSS[gb], qlo); atomicAdd(&sgSS[gb+1], qhi);
      *(uint4*)(dst + g*8) = pb8(v);
    }
  }
  __syncthreads();
  if (t < 32){
    atomicAdd(&SG3[(b*32+t)*2],   sgS[t]);
    atomicAdd(&SG3[(b*32+t)*2+1], sgSS[t]);
  }
}

// ---------------- k_s3: AdaGN -> mlp1(silu) -> mlp2 -> +XRb => XRb + SG4 ----------------
__global__ __launch_bounds__(256) void k_s3(
    unsigned short* __restrict__ XRb,
    const float* __restrict__ SG3, float* __restrict__ SG4,
    const unsigned short* __restrict__ W1, const float* __restrict__ b1,
    const unsigned short* __restrict__ W2, const float* __restrict__ b2,
    const float* __restrict__ gnw, const float* __restrict__ gnb,
    const float* __restrict__ scsh)
{
  __shared__ __align__(16) unsigned short Xs[64*136];
  __shared__ __align__(16) char UN[45056];  // As1 17408 | Hs 9216 | As2 18432 ; OT overlays As1
  __shared__ float An[128], Bn[128];
  __shared__ float sgS[32], sgSS[32];
  unsigned short* As1 = (unsigned short*)UN;
  unsigned short* Hs  = (unsigned short*)(UN + 17408);
  unsigned short* As2 = (unsigned short*)(UN + 26624);
  unsigned short* OT  = (unsigned short*)UN;
  int t = threadIdx.x;
  int p0 = blockIdx.x << 6;
  int b = p0 >> 14;
  if (t < 128){
    int g = t >> 2;
    float S = SG3[(b*32+g)*2], SS = SG3[(b*32+g)*2+1];
    float m = S*(1.f/65536.f);
    float r = rsqrtf(SS*(1.f/65536.f) - m*m + EPSV);
    float sc = 1.f + scsh[b*256 + t];
    float sh = scsh[b*256 + 128 + t];
    An[t] = r*gnw[t]*sc;
    Bn[t] = (gnb[t] - m*r*gnw[t])*sc + sh;
  }
  if (t < 32){ sgS[t]=0.f; sgSS[t]=0.f; }
  __syncthreads();
  {
    int px = t >> 2, kh = (t & 3) << 5;
    const unsigned short* src = XRb + (size_t)(p0+px)*128 + kh;
    unsigned short* dst = Xs + px*136 + kh;
    #pragma unroll
    for (int j = 0; j < 4; ++j){
      uint4 u = *(const uint4*)(src + j*8);
      float f[8], g[8];
      ub8(u, f);
      int c = kh + j*8;
      #pragma unroll
      for (int e = 0; e < 8; ++e) g[e] = fmaf(f[e], An[c+e], Bn[c+e]);
      *(uint4*)(dst + j*8) = pb8(g);
    }
  }
  int lane = t & 63, wv = t >> 6, quad = lane >> 4, l15 = lane & 15;
  int hbv = (wv & 1) << 5, pxb = (wv >> 1) << 5, ob2 = wv << 5;
  f32x4 acc2[2][4];
  #pragma unroll
  for (int i=0;i<2;++i)
    #pragma unroll
    for (int j=0;j<4;++j){ f32x4 z={0.f,0.f,0.f,0.f}; acc2[i][j]=z; }
  for (int hc = 0; hc < 8; ++hc){
    __syncthreads();
    { int hr = t >> 2, kh = (t & 3) << 5;
      const unsigned short* src = W1 + (size_t)(hc*64+hr)*128 + kh;
      unsigned short* dst = As1 + hr*136 + kh;
      #pragma unroll
      for (int j = 0; j < 4; ++j) *(uint4*)(dst + j*8) = *(const uint4*)(src + j*8);
    }
    { int o = t >> 1, kh = (t & 1) << 5;
      const unsigned short* src = W2 + (size_t)o*512 + hc*64 + kh;
      unsigned short* dst = As2 + o*72 + kh;
      #pragma unroll
      for (int j = 0; j < 4; ++j) *(uint4*)(dst + j*8) = *(const uint4*)(src + j*8);
    }
    __syncthreads();
    {
      f32x4 a1[2][2];
      #pragma unroll
      for (int i=0;i<2;++i)
        #pragma unroll
        for (int j=0;j<2;++j){ f32x4 z={0.f,0.f,0.f,0.f}; a1[i][j]=z; }
      #pragma unroll
      for (int s = 0; s < 4; ++s){
        bf16x8 af[2], bx[2];
        #pragma unroll
        for (int i=0;i<2;++i) af[i] = *(const bf16x8*)(As1 + (hbv+i*16+l15)*136 + s*32 + quad*8);
        #pragma unroll
        for (int j=0;j<2;++j) bx[j] = *(const bf16x8*)(Xs + (pxb+j*16+l15)*136 + s*32 + quad*8);
        #pragma unroll
        for (int i=0;i<2;++i)
          #pragma unroll
          for (int j=0;j<2;++j)
            a1[i][j] = __builtin_amdgcn_mfma_f32_16x16x32_bf16(af[i], bx[j], a1[i][j], 0,0,0);
      }
      #pragma unroll
      for (int i = 0; i < 2; ++i){
        int hl = hbv + i*16 + (quad<<2);
        float4 bv = *(const float4*)(b1 + hc*64 + hl);
        #pragma unroll
        for (int j = 0; j < 2; ++j){
          int px = pxb + j*16 + l15;
          float v0=a1[i][j][0]+bv.x, v1=a1[i][j][1]+bv.y, v2=a1[i][j][2]+bv.z, v3=a1[i][j][3]+bv.w;
          v0*=sigmoidf_(v0); v1*=sigmoidf_(v1); v2*=sigmoidf_(v2); v3*=sigmoidf_(v3);
          *(unsigned int*)(Hs + px*72 + hl)     = pk2(v0, v1);
          *(unsigned int*)(Hs + px*72 + hl + 2) = pk2(v2, v3);
        }
      }
    }
    __syncthreads();
    #pragma unroll
    for (int s = 0; s < 2; ++s){
      bf16x8 af2[2], bh[4];
      #pragma unroll
      for (int i=0;i<2;++i) af2[i] = *(const bf16x8*)(As2 + (ob2+i*16+l15)*72 + s*32 + quad*8);
      #pragma unroll
      for (int j=0;j<4;++j) bh[j] = *(const bf16x8*)(Hs + (j*16+l15)*72 + s*32 + quad*8);
      #pragma unroll
      for (int i=0;i<2;++i)
        #pragma unroll
        for (int j=0;j<4;++j)
          acc2[i][j] = __builtin_amdgcn_mfma_f32_16x16x32_bf16(af2[i], bh[j], acc2[i][j], 0,0,0);
    }
  }
  __syncthreads();
  #pragma unroll
  for (int i = 0; i < 2; ++i){
    int o = ob2 + i*16 + (quad<<2);
    float4 bv = *(const float4*)(b2 + o);
    #pragma unroll
    for (int j = 0; j < 4; ++j){
      int px = j*16 + l15;
      uint2 w; w.x = pk2(acc2[i][j][0]+bv.x, acc2[i][j][1]+bv.y);
      w.y = pk2(acc2[i][j][2]+bv.z, acc2[i][j][3]+bv.w);
      *(uint2*)(OT + px*136 + o) = w;
    }
  }
  __syncthreads();
  {
    int px = t >> 2, c0 = (t & 3) << 5;
    unsigned short* dst = XRb + (size_t)(p0+px)*128 + c0;
    #pragma unroll
    for (int g = 0; g < 4; ++g){
      uint4 hu = *(const uint4*)(OT + px*136 + c0 + g*8);
      uint4 ru = *(const uint4*)(dst + g*8);
      float hf[8], rf[8], v[8];
      ub8(hu, hf); ub8(ru, rf);
      #pragma unroll
      for (int e = 0; e < 8; ++e) v[e] = hf[e] + rf[e];
      float slo = v[0]+v[1]+v[2]+v[3], shi = v[4]+v[5]+v[6]+v[7];
      float qlo = v[0]*v[0]+v[1]*v[1]+v[2]*v[2]+v[3]*v[3];
      float qhi = v[4]*v[4]+v[5]*v[5]+v[6]*v[6]+v[7]*v[7];
      int gb = (c0 + g*8) >> 2;
      atomicAdd(&sgS[gb], slo);  atomicAdd(&sgS[gb+1], shi);
      atomicAdd(&sgSS[gb], qlo); atomicAdd(&sgSS[gb+1], qhi);
      *(uint4*)(dst + g*8) = pb8(v);
    }
  }
  __syncthreads();
  if (t < 32){
    atomicAdd(&SG4[(b*32+t)*2],   sgS[t]);
    atomicAdd(&SG4[(b*32+t)*2+1], sgSS[t]);
  }
}

// ---------------- k_dw: GN -> dw3x3 -> +b -> silu => DWOb bf16 ----------------
__global__ __launch_bounds__(256) void k_dw(
    const unsigned short* __restrict__ XRb, const float* __restrict__ SG4,
    const float* __restrict__ gnw, const float* __restrict__ gnb,
    const float* __restrict__ dww, const float* __restrict__ dwb,
    unsigned short* __restrict__ DWOb)
{
  __shared__ float wt[9*128];
  __shared__ float An[128], Bn[128];
  int t = threadIdx.x;
  int blk = blockIdx.x;
  int b = blk >> 8;
  int rem = blk & 255;
  int h0 = (rem >> 3) << 2;
  int w0 = (rem & 7) << 4;
  if (t < 128){
    int g = t >> 2;
    float S = SG4[(b*32+g)*2], SS = SG4[(b*32+g)*2+1];
    float m = S*(1.f/65536.f);
    float r = rsqrtf(SS*(1.f/65536.f) - m*m + EPSV);
    float A = r*gnw[t];
    An[t] = A; Bn[t] = gnb[t] - m*A;
  }
  for (int j = t; j < 1152; j += 256){ int c = j/9, tap = j%9; wt[tap*128 + c] = dww[j]; }
  __syncthreads();
  int pxl = t & 63, cg = t >> 6;
  int ty = pxl >> 4, tx = pxl & 15;
  int h = h0 + ty, w = w0 + tx;
  int c0 = cg << 5;
  float acc[32];
  #pragma unroll
  for (int g = 0; g < 8; ++g){
    float4 bv = *(const float4*)(dwb + c0 + g*4);
    acc[g*4+0]=bv.x; acc[g*4+1]=bv.y; acc[g*4+2]=bv.z; acc[g*4+3]=bv.w;
  }
  #pragma unroll
  for (int dy = -1; dy <= 1; ++dy){
    int hh = h + dy;
    if (hh < 0 || hh > 127) continue;
    #pragma unroll
    for (int dx = -1; dx <= 1; ++dx){
      int wn = w + dx;
      if (wn < 0 || wn > 127) continue;
      const unsigned short* xp = XRb + (size_t)(b*IMGP + hh*128 + wn)*128 + c0;
      const float* wp = wt + ((dy+1)*3 + (dx+1))*128 + c0;
      #pragma unroll
      for (int g = 0; g < 4; ++g){
        uint4 u = *(const uint4*)(xp + g*8);
        float f[8];
        ub8(u, f);
        int c = c0 + g*8;
        #pragma unroll
        for (int e = 0; e < 8; ++e)
          acc[g*8+e] = fmaf(wp[g*8+e], fmaf(An[c+e], f[e], Bn[c+e]), acc[g*8+e]);
      }
    }
  }
  unsigned short* dst = DWOb + (size_t)(b*IMGP + h*128 + w)*128 + c0;
  #pragma unroll
  for (int g = 0; g < 4; ++g){
    float v[8];
    #pragma unroll
    for (int e = 0; e < 8; ++e){ float x = acc[g*8+e]; v[e] = x * sigmoidf_(x); }
    *(uint4*)(dst + g*8) = pb8(v);
  }
}

// ---------------- k_s4: pw 1x1 (swapped operands) -> +XRb => out fp32 [c][p] ----------------
__global__ __launch_bounds__(256) void k_s4(
    const unsigned short* __restrict__ DWOb,
    const unsigned short* __restrict__ Wpw, const float* __restrict__ bias,
    const unsigned short* __restrict__ XRb, float* __restrict__ out)
{
  __shared__ __align__(16) char UN[36864];  // PXs 18432 | Ws 18432 ; RS [128][136] overlay
  unsigned short* PXs = (unsigned short*)UN;
  unsigned short* Ws  = (unsigned short*)(UN + 18432);
  unsigned short* RS  = (unsigned short*)UN;
  int t = threadIdx.x;
  int p0 = blockIdx.x << 7;
  int b = p0 >> 14;
  int hw0 = p0 & 16383;
  int lane = t & 63, wv = t >> 6, quad = lane >> 4, l15 = lane & 15;
  int pb = (wv >> 1) << 6, ob = (wv & 1) << 6;
  f32x4 acc[4][4];
  #pragma unroll
  for (int i=0;i<4;++i)
    #pragma unroll
    for (int j=0;j<4;++j){ f32x4 z={0.f,0.f,0.f,0.f}; acc[i][j]=z; }
  for (int kc = 0; kc < 2; ++kc){
    if (kc) __syncthreads();
    { int px = t >> 1, kh = (t & 1) << 5;
      const unsigned short* src = DWOb + (size_t)(p0+px)*128 + kc*64 + kh;
      unsigned short* dst = PXs + px*72 + kh;
      #pragma unroll
      for (int j = 0; j < 4; ++j) *(uint4*)(dst + j*8) = *(const uint4*)(src + j*8);
    }
    { int o = t >> 1, kh = (t & 1) << 5;
      const unsigned short* src = Wpw + o*128 + kc*64 + kh;
      unsigned short* dst = Ws + o*72 + kh;
      #pragma unroll
      for (int j = 0; j < 4; ++j) *(uint4*)(dst + j*8) = *(const uint4*)(src + j*8);
    }
    __syncthreads();
    #pragma unroll
    for (int s = 0; s < 2; ++s){
      bf16x8 ax[4], bw[4];
      #pragma unroll
      for (int i=0;i<4;++i) ax[i] = *(const bf16x8*)(PXs + (pb+i*16+l15)*72 + s*32 + quad*8);
      #pragma unroll
      for (int j=0;j<4;++j) bw[j] = *(const bf16x8*)(Ws + (ob+j*16+l15)*72 + s*32 + quad*8);
      #pragma unroll
      for (int i=0;i<4;++i)
        #pragma unroll
        for (int j=0;j<4;++j)
          acc[i][j] = __builtin_amdgcn_mfma_f32_16x16x32_bf16(ax[i], bw[j], acc[i][j], 0,0,0);
    }
  }
  __syncthreads();
  {
    int px = t >> 1, ch = (t & 1) << 6;
    const unsigned short* src = XRb + (size_t)(p0+px)*128 + ch;
    unsigned short* dst = RS + px*136 + ch;
    #pragma unroll
    for (int g = 0; g < 8; ++g) *(uint4*)(dst + g*8) = *(const uint4*)(src + g*8);
  }
  __syncthreads();
  #pragma unroll
  for (int j = 0; j < 4; ++j){
    int o = ob + j*16 + l15;
    float bv = bias[o];
    float* orow = out + (size_t)(b*128 + o)*IMGP + hw0;
    #pragma unroll
    for (int i = 0; i < 4; ++i){
      int pxq = pb + i*16 + (quad << 2);
      float4 v;
      v.x = acc[i][j][0] + bv + bf2f(RS[(pxq+0)*136 + o]);
      v.y = acc[i][j][1] + bv + bf2f(RS[(pxq+1)*136 + o]);
      v.z = acc[i][j][2] + bv + bf2f(RS[(pxq+2)*136 + o]);
      v.w = acc[i][j][3] + bv + bf2f(RS[(pxq+3)*136 + o]);
      *(float4*)(orow + pxq) = v;
    }
  }
}

extern "C" void kernel_launch(void* const* d_in, const int* in_sizes, int n_in,
                              void* d_out, int out_size, void* d_ws, size_t ws_size,
                              hipStream_t stream)
{
  const float* x0   = (const float*)d_in[0];
  const float* temb = (const float*)d_in[1];
  const float* gn1w = (const float*)d_in[2];
  const float* gn1b = (const float*)d_in[3];
  const float* t1w1 = (const float*)d_in[4];
  const float* t1b1 = (const float*)d_in[5];
  const float* t1w2 = (const float*)d_in[6];
  const float* t1b2 = (const float*)d_in[7];
  const float* specw= (const float*)d_in[8];
  const float* specb= (const float*)d_in[9];
  const float* modew= (const float*)d_in[10];
  const float* gn2w = (const float*)d_in[11];
  const float* gn2b = (const float*)d_in[12];
  const float* t2w1 = (const float*)d_in[13];
  const float* t2b1 = (const float*)d_in[14];
  const float* t2w2 = (const float*)d_in[15];
  const float* t2b2 = (const float*)d_in[16];
  const float* qkvw = (const float*)d_in[17];
  const float* qkvb = (const float*)d_in[18];
  const float* projw= (const float*)d_in[19];
  const float* projb= (const float*)d_in[20];
  const float* relb = (const float*)d_in[21];
  const float* gn3w = (const float*)d_in[22];
  const float* gn3b = (const float*)d_in[23];
  const float* t3w1 = (const float*)d_in[24];
  const float* t3b1 = (const float*)d_in[25];
  const float* t3w2 = (const float*)d_in[26];
  const float* t3b2 = (const float*)d_in[27];
  const float* mlpw1= (const float*)d_in[28];
  const float* mlpb1= (const float*)d_in[29];
  const float* mlpw2= (const float*)d_in[30];
  const float* mlpb2= (const float*)d_in[31];
  const float* sbgnw= (const float*)d_in[32];
  const float* sbgnb= (const float*)d_in[33];
  const float* dww  = (const float*)d_in[34];
  const float* dwb  = (const float*)d_in[35];
  const float* pww  = (const float*)d_in[36];
  const float* pwb  = (const float*)d_in[37];
  float* out = (float*)d_out;

  char* ws = (char*)d_ws;
  float* SC  = (float*)ws;
  float* SG  = (float*)(ws + 32768);
  float* SG1 = SG, *SG2 = SG+512, *SG3 = SG+1024, *SG4 = SG+1536;
  unsigned short* WBF = (unsigned short*)(ws + 65536);
  unsigned short* Wspec = WBF;
  unsigned short* Wqkv  = WBF + 16384;
  unsigned short* Wproj = WBF + 65536;
  unsigned short* Wmlp1 = WBF + 81920;
  unsigned short* Wmlp2 = WBF + 147456;
  unsigned short* Wpw   = WBF + 212992;
  unsigned short* X0b = (unsigned short*)(ws + (1u<<20));                     // 32 MiB
  unsigned short* XRb = (unsigned short*)(ws + (1u<<20) + ((size_t)32<<20));  // 32 MiB
  unsigned short* QKV = (unsigned short*)(ws + (1u<<20) + ((size_t)64<<20));  // 96 MiB
  unsigned short* DWOb = QKV;                                                 // reuse (32 MiB)

  hipMemsetAsync(SG, 0, 4*512*sizeof(float), stream);

  k_prep<<<896, 256, 0, stream>>>(specw, qkvw, projw, mlpw1, mlpw2, pww, WBF);
  k_tmlp<<<dim3(8,3), 256, 0, stream>>>(temb,
      t1w1,t1b1,t1w2,t1b2, t2w1,t2b1,t2w2,t2b2, t3w1,t3b1,t3w2,t3b2, SC);
  k_pre<<<2048, 256, 0, stream>>>(x0, X0b, SG1);
  k_s1<<<1024, 256, 0, stream>>>(X0b, SG1, SG2, Wspec, specb,
      gn1w, gn1b, SC + 0, modew, XRb);
  k_qkv<<<dim3(1024,3), 256, 0, stream>>>(XRb, SG2, Wqkv, qkvb,
      gn2w, gn2b, SC + 2048, QKV);
  k_ap<<<1024, 256, 0, stream>>>(QKV, Wproj, projb, relb, XRb, SG3);
  k_s3<<<2048, 256, 0, stream>>>(XRb, SG3, SG4, Wmlp1, mlpb1, Wmlp2, mlpb2,
      gn3w, gn3b, SC + 4096);
  k_dw<<<2048, 256, 0, stream>>>(XRb, SG4, sbgnw, sbgnb, dww, dwb, DWOb);
  k_s4<<<1024, 256, 0, stream>>>(DWOb, Wpw, pwb, XRb, out);
}